// Round 6
// baseline (428.947 us; speedup 1.0000x reference)
//
#include <hip/hip_runtime.h>

#define N_NODES 100000
#define N_EDGES 1600000
#define D_NODE 96
#define D_EDGE 32
#define N_GRAPHS 128
#define BN_EPS 1e-5f

#define EDGE_BLOCKS 2048
#define EDGE_THREADS 256
#define EDGE_STRIDE (EDGE_BLOCKS * EDGE_THREADS)   // 524288 -> 3.05 edges/thread

typedef float f2 __attribute__((ext_vector_type(2)));

// ---------------- prep: fold BN into weights, TRANSPOSED for packed-k FMA ----------------
// w1nT[96][16] : w1nT[j][k] = A[k] * W1[k][j]        (k-pairs contiguous -> v_pk_fma_f32)
// w1eT[32][16] : w1eT[j][k] = A[k] * W1[k][96+j]
// cw[0:16]  = C[k] = A[k]*(b1[k]-mean[k]) + beta[k]
// cw[16:32] = W2[k]
// cw[32]    = b2
__global__ void prep_kernel(const float* __restrict__ W1, const float* __restrict__ b1,
                            const float* __restrict__ gamma, const float* __restrict__ beta,
                            const float* __restrict__ rmean, const float* __restrict__ rvar,
                            const float* __restrict__ W2, const float* __restrict__ b2,
                            float* __restrict__ w1nT, float* __restrict__ w1eT,
                            float* __restrict__ cw) {
    int t = threadIdx.x;
    if (t < 16) {
        float A = gamma[t] * rsqrtf(rvar[t] + BN_EPS);
        cw[t] = A * (b1[t] - rmean[t]) + beta[t];
        cw[16 + t] = W2[t];
        for (int j = 0; j < D_NODE; ++j)
            w1nT[j * 16 + t] = A * W1[t * (D_NODE + D_EDGE) + j];
        for (int j = 0; j < D_EDGE; ++j)
            w1eT[j * 16 + t] = A * W1[t * (D_NODE + D_EDGE) + D_NODE + j];
    }
    if (t == 16) cw[32] = b2[0];
}

// ---------------- node projection: y[n][k] = sum_j x[n][j]*w1nT[j][k] ----------------
// 4 waves/block, wave q owns k-quad [4q,4q+4); packed-k FMA (2 f2 accumulators).
__global__ __launch_bounds__(256) void node_proj_kernel(const float* __restrict__ x,
                                                        const float* __restrict__ w1nT,
                                                        float* __restrict__ y) {
    int t = threadIdx.x;
    int q = t >> 6;                          // wave index 0..3 (uniform per wave)
    int n = blockIdx.x * 64 + (t & 63);
    if (n >= N_NODES) return;
    const float4* xr = (const float4*)(x + (size_t)n * D_NODE);
    f2 acc0 = {0.f, 0.f}, acc1 = {0.f, 0.f};
#pragma unroll
    for (int j4 = 0; j4 < D_NODE / 4; ++j4) {
        float4 xv = xr[j4];
#pragma unroll
        for (int u = 0; u < 4; ++u) {
            float xs = (u == 0) ? xv.x : (u == 1) ? xv.y : (u == 2) ? xv.z : xv.w;
            f2 xs2 = {xs, xs};
            const f2* wp = (const f2*)(w1nT + (j4 * 4 + u) * 16 + q * 4);  // uniform -> s_load
            acc0 = __builtin_elementwise_fma(xs2, wp[0], acc0);
            acc1 = __builtin_elementwise_fma(xs2, wp[1], acc1);
        }
    }
    ((float4*)(y + (size_t)n * 16))[q] = make_float4(acc0.x, acc0.y, acc1.x, acc1.y);
}

// ---------------- edge kernel: grid-stride, packed-k MLP, 1-ahead index prefetch ----------------
// Per iteration: use prefetched (s,d); issue y-gather; issue ea loads; prefetch next (s,d);
// MLP (independent of gather); epilogue consumes gather; LDS bin atomic.
// The eidx->gather chain of iter i+1 is fully covered by iter i's body.
__global__ __launch_bounds__(EDGE_THREADS, 7) void edge_kernel(
    const float* __restrict__ ea, const int* __restrict__ eidx,
    const int* __restrict__ batch, const float* __restrict__ y,
    const float* __restrict__ w1eT, const float* __restrict__ cw,
    float* __restrict__ partials) {
    __shared__ float bins[N_GRAPHS];
    int t = threadIdx.x;
    if (t < N_GRAPHS) bins[t] = 0.f;
    __syncthreads();

    int e = blockIdx.x * EDGE_THREADS + t;        // < EDGE_STRIDE <= N_EDGES
    int sn = eidx[e];
    int dn = eidx[N_EDGES + e];
    float b2v = cw[32];

    while (true) {
        int g = batch[dn];

        // y gather: issued first, consumed only in the epilogue
        float ya[16];
        const float4* yr = (const float4*)(y + (size_t)sn * 16);
#pragma unroll
        for (int qq = 0; qq < 4; ++qq) ((float4*)ya)[qq] = yr[qq];

        // streaming edge features
        const float4* er = (const float4*)(ea + (size_t)e * D_EDGE);
        float4 ev[8];
#pragma unroll
        for (int i = 0; i < 8; ++i) ev[i] = er[i];

        // prefetch next iteration's index chain (independent of everything below)
        int e_next = e + EDGE_STRIDE;
        bool more = (e_next < N_EDGES);
        int sn_next = 0, dn_next = 0;
        if (more) {
            sn_next = eidx[e_next];
            dn_next = eidx[N_EDGES + e_next];
        }

        // packed-k MLP: acc[k2] = (h_{2k2}, h_{2k2+1}) partials
        f2 acc[8];
#pragma unroll
        for (int k2 = 0; k2 < 8; ++k2) acc[k2] = (f2){0.f, 0.f};
        const float* evs = (const float*)ev;       // static indexing after unroll -> VGPRs
#pragma unroll
        for (int j = 0; j < D_EDGE; ++j) {
            float b = evs[j];
            f2 bb = {b, b};
            const f2* wp = (const f2*)(w1eT + j * 16);   // uniform -> s_load
#pragma unroll
            for (int k2 = 0; k2 < 8; ++k2)
                acc[k2] = __builtin_elementwise_fma(bb, wp[k2], acc[k2]);
        }

        // epilogue: bias + relu + W2 dot (consumes the gather)
        const f2* ya2 = (const f2*)ya;
        const f2* c2  = (const f2*)cw;
        const f2* w2p = (const f2*)(cw + 16);
        f2 m2 = {0.f, 0.f};
#pragma unroll
        for (int k2 = 0; k2 < 8; ++k2) {
            f2 h = acc[k2] + ya2[k2] + c2[k2];
            h = __builtin_elementwise_max(h, (f2){0.f, 0.f});
            m2 = __builtin_elementwise_fma(h, w2p[k2], m2);
        }
        float msg = m2.x + m2.y + b2v;
        atomicAdd(&bins[g], msg);

        if (!more) break;
        e = e_next; sn = sn_next; dn = dn_next;
    }

    __syncthreads();
    // contiguous per-block row: coalesced, no write-allocate churn
    if (t < N_GRAPHS) partials[(size_t)blockIdx.x * N_GRAPHS + t] = bins[t];
}

// ---------------- final reduce: out[g] = sum_b partials[b][g] ----------------
__global__ __launch_bounds__(256) void reduce_kernel(const float* __restrict__ partials,
                                                     float* __restrict__ out) {
    __shared__ float sm[256];
    int g = blockIdx.x;
    float acc = 0.f;
    for (int b = threadIdx.x; b < EDGE_BLOCKS; b += 256)
        acc += partials[(size_t)b * N_GRAPHS + g];
    sm[threadIdx.x] = acc;
    __syncthreads();
    for (int w = 128; w > 0; w >>= 1) {
        if (threadIdx.x < w) sm[threadIdx.x] += sm[threadIdx.x + w];
        __syncthreads();
    }
    if (threadIdx.x == 0) out[g] = sm[0];
}

extern "C" void kernel_launch(void* const* d_in, const int* in_sizes, int n_in,
                              void* d_out, int out_size, void* d_ws, size_t ws_size,
                              hipStream_t stream) {
    const float* x     = (const float*)d_in[0];
    const float* ea    = (const float*)d_in[1];
    const int*   eidx  = (const int*)d_in[2];
    const int*   batch = (const int*)d_in[3];
    const float* W1    = (const float*)d_in[4];
    const float* b1    = (const float*)d_in[5];
    const float* gamma = (const float*)d_in[6];
    const float* beta  = (const float*)d_in[7];
    const float* rmean = (const float*)d_in[8];
    const float* rvar  = (const float*)d_in[9];
    const float* W2    = (const float*)d_in[10];
    const float* b2    = (const float*)d_in[11];
    float* out = (float*)d_out;

    float* ws = (float*)d_ws;
    // ws layout (floats):
    float* w1nT     = ws;                    // 96*16 = 1536
    float* w1eT     = ws + 1536;             // 32*16 = 512
    float* cw       = ws + 2048;             // 33 (pad to 2048)
    float* y        = ws + 4096;             // N_NODES*16 = 1,600,000
    float* partials = ws + 4096 + (size_t)N_NODES * 16;  // EDGE_BLOCKS*128 = 262,144

    prep_kernel<<<1, 64, 0, stream>>>(W1, b1, gamma, beta, rmean, rvar, W2, b2, w1nT, w1eT, cw);
    node_proj_kernel<<<(N_NODES + 63) / 64, 256, 0, stream>>>(x, w1nT, y);
    edge_kernel<<<EDGE_BLOCKS, EDGE_THREADS, 0, stream>>>(ea, eidx, batch, y, w1eT, cw, partials);
    reduce_kernel<<<N_GRAPHS, 256, 0, stream>>>(partials, out);
}

// Round 7
// 374.427 us; speedup vs baseline: 1.1456x; 1.1456x over previous
//
#include <hip/hip_runtime.h>
#include <stdint.h>

#define N_NODES 100000
#define N_EDGES 1600000
#define D_NODE 96
#define D_EDGE 32
#define N_GRAPHS 128
#define BN_EPS 1e-5f

#define EB_THREADS 256
#define CHUNK 256                       // edges per chunk (= threads per block)
#define CHUNKS_PER_BLOCK 5
#define EB_BLOCKS 1250                  // 1250 * 5 * 256 == 1,600,000 exactly

typedef float f2 __attribute__((ext_vector_type(2)));

// async global->LDS DMA, 16B per lane; LDS dest = wave-uniform base + lane*16 (HW rule)
__device__ __forceinline__ void stage16(const float* g, float* l) {
    __builtin_amdgcn_global_load_lds(
        (const __attribute__((address_space(1))) void*)g,
        (__attribute__((address_space(3))) void*)l, 16, 0, 0);
}

// ---------------- prep: fold BN into weights, TRANSPOSED for packed-k FMA ----------------
// w1nT[96][16] : w1nT[j][k] = A[k] * W1[k][j]
// w1eT[32][16] : w1eT[j][k] = A[k] * W1[k][96+j]
// cw[0:16]=C[k]  cw[16:32]=W2[k]  cw[32]=b2
__global__ void prep_kernel(const float* __restrict__ W1, const float* __restrict__ b1,
                            const float* __restrict__ gamma, const float* __restrict__ beta,
                            const float* __restrict__ rmean, const float* __restrict__ rvar,
                            const float* __restrict__ W2, const float* __restrict__ b2,
                            float* __restrict__ w1nT, float* __restrict__ w1eT,
                            float* __restrict__ cw) {
    int t = threadIdx.x;
    if (t < 16) {
        float A = gamma[t] * rsqrtf(rvar[t] + BN_EPS);
        cw[t] = A * (b1[t] - rmean[t]) + beta[t];
        cw[16 + t] = W2[t];
        for (int j = 0; j < D_NODE; ++j)
            w1nT[j * 16 + t] = A * W1[t * (D_NODE + D_EDGE) + j];
        for (int j = 0; j < D_EDGE; ++j)
            w1eT[j * 16 + t] = A * W1[t * (D_NODE + D_EDGE) + D_NODE + j];
    }
    if (t == 16) cw[32] = b2[0];
}

// ---------------- node projection: y[n][k] = sum_j x[n][j]*w1nT[j][k] ----------------
// R0-proven mapping (1 thread/node, x row read ONCE) + packed-k f2 FMA.
__global__ __launch_bounds__(256) void node_proj_kernel(const float* __restrict__ x,
                                                        const float* __restrict__ w1nT,
                                                        float* __restrict__ y) {
    int n = blockIdx.x * 256 + threadIdx.x;
    if (n >= N_NODES) return;
    const float4* xr = (const float4*)(x + (size_t)n * D_NODE);
    f2 acc[8];
#pragma unroll
    for (int k2 = 0; k2 < 8; ++k2) acc[k2] = (f2){0.f, 0.f};
#pragma unroll
    for (int j4 = 0; j4 < D_NODE / 4; ++j4) {
        float4 xv = xr[j4];
#pragma unroll
        for (int u = 0; u < 4; ++u) {
            float xs = (u == 0) ? xv.x : (u == 1) ? xv.y : (u == 2) ? xv.z : xv.w;
            f2 xs2 = {xs, xs};
            const f2* wp = (const f2*)(w1nT + (j4 * 4 + u) * 16);   // uniform -> s_load
#pragma unroll
            for (int k2 = 0; k2 < 8; ++k2)
                acc[k2] = __builtin_elementwise_fma(xs2, wp[k2], acc[k2]);
        }
    }
    float4* yr = (float4*)(y + (size_t)n * 16);
#pragma unroll
    for (int q = 0; q < 4; ++q)
        yr[q] = make_float4(acc[2 * q].x, acc[2 * q].y, acc[2 * q + 1].x, acc[2 * q + 1].y);
}

// ---------------- edge kernel: async LDS-staged ea stream + decoupled y gather ----------------
// Per chunk of 256 edges: stage next chunk via global_load_lds (fire-and-forget),
// gather y/idx for current chunk, MLP from LDS, LDS-bin atomic; barrier drains the stage.
// LDS layout [edge][f4] with XOR swizzle f4^(e&7): swizzle pre-applied to GLOBAL source
// (rule: gld_lds dest must stay linear), re-applied on the ds_read side.
__global__ __launch_bounds__(EB_THREADS, 2) void edge_kernel(
    const float* __restrict__ ea, const int* __restrict__ eidx,
    const int* __restrict__ batch, const float* __restrict__ y,
    const float* __restrict__ w1eT, const float* __restrict__ cw,
    float* __restrict__ partials) {
    __shared__ float4 ebuf[2][CHUNK * 8];   // 2 x 32 KB
    __shared__ float bins[N_GRAPHS];
    const int t = threadIdx.x;
    if (t < N_GRAPHS) bins[t] = 0.f;

    const int wave = t >> 6;
    const int g8 = (t & 63) >> 3;           // lane group 0..7
    const int s8 = t & 7;                   // slot within edge
    const int f4log = s8 ^ g8;              // pre-swizzled feature index (e&7 == g8)

    const int base = blockIdx.x * (CHUNKS_PER_BLOCK * CHUNK);

    // prologue: stage chunk 0 into buf 0 (8 gld_lds per wave, 1KB each)
    {
        const float* sb = ea + (size_t)base * D_EDGE;
#pragma unroll
        for (int i = 0; i < 8; ++i) {
            int k = wave * 8 + i;
            int e = k * 8 + g8;
            stage16(sb + (size_t)e * D_EDGE + f4log * 4, (float*)&ebuf[0][k * 64]);
        }
    }
    asm volatile("s_waitcnt vmcnt(0)" ::: "memory");
    __syncthreads();

    float b2v = cw[32];
    int cur = 0;
#pragma unroll 1
    for (int c = 0; c < CHUNKS_PER_BLOCK; ++c) {
        int cb = base + c * CHUNK;

        // async-stage next chunk; completion enforced by end-of-iteration barrier,
        // latency covered by this iteration's gather + MLP
        if (c + 1 < CHUNKS_PER_BLOCK) {
            const float* sb = ea + (size_t)(cb + CHUNK) * D_EDGE;
#pragma unroll
            for (int i = 0; i < 8; ++i) {
                int k = wave * 8 + i;
                int e = k * 8 + g8;
                stage16(sb + (size_t)e * D_EDGE + f4log * 4, (float*)&ebuf[cur ^ 1][k * 64]);
            }
        }

        // index chain + y gather for current chunk (coalesced eidx, random y)
        int e = cb + t;
        int sn = eidx[e];
        int dn = eidx[N_EDGES + e];
        int g = batch[dn];

        float ya[16];
        const float4* yr = (const float4*)(y + (size_t)sn * 16);
#pragma unroll
        for (int qq = 0; qq < 4; ++qq) ((float4*)ya)[qq] = yr[qq];

        // edge features from LDS (swizzle-corrected reads, 2-way max bank aliasing)
        float4 ev[8];
#pragma unroll
        for (int f = 0; f < 8; ++f) ev[f] = ebuf[cur][t * 8 + (f ^ (t & 7))];

        // packed-k MLP (bit-identical to R5)
        f2 acc[8];
#pragma unroll
        for (int k2 = 0; k2 < 8; ++k2) acc[k2] = (f2){0.f, 0.f};
        const float* evs = (const float*)ev;
#pragma unroll
        for (int j = 0; j < D_EDGE; ++j) {
            float b = evs[j];
            f2 bb = {b, b};
            const f2* wp = (const f2*)(w1eT + j * 16);   // uniform -> s_load
#pragma unroll
            for (int k2 = 0; k2 < 8; ++k2)
                acc[k2] = __builtin_elementwise_fma(bb, wp[k2], acc[k2]);
        }

        const f2* ya2 = (const f2*)ya;
        const f2* c2 = (const f2*)cw;
        const f2* w2p = (const f2*)(cw + 16);
        f2 m2 = {0.f, 0.f};
#pragma unroll
        for (int k2 = 0; k2 < 8; ++k2) {
            f2 h = acc[k2] + ya2[k2] + c2[k2];
            h = __builtin_elementwise_max(h, (f2){0.f, 0.f});
            m2 = __builtin_elementwise_fma(h, w2p[k2], m2);
        }
        atomicAdd(&bins[g], m2.x + m2.y + b2v);

        asm volatile("s_waitcnt vmcnt(0)" ::: "memory");
        __syncthreads();                 // drains stage(c+1) + releases ebuf[cur]
        cur ^= 1;
    }

    if (t < N_GRAPHS) partials[(size_t)blockIdx.x * N_GRAPHS + t] = bins[t];
}

// ---------------- final reduce: out[g] = sum_b partials[b][g] ----------------
__global__ __launch_bounds__(256) void reduce_kernel(const float* __restrict__ partials,
                                                     float* __restrict__ out) {
    __shared__ float sm[256];
    int g = blockIdx.x;
    float acc = 0.f;
    for (int b = threadIdx.x; b < EB_BLOCKS; b += 256)
        acc += partials[(size_t)b * N_GRAPHS + g];
    sm[threadIdx.x] = acc;
    __syncthreads();
    for (int w = 128; w > 0; w >>= 1) {
        if (threadIdx.x < w) sm[threadIdx.x] += sm[threadIdx.x + w];
        __syncthreads();
    }
    if (threadIdx.x == 0) out[g] = sm[0];
}

extern "C" void kernel_launch(void* const* d_in, const int* in_sizes, int n_in,
                              void* d_out, int out_size, void* d_ws, size_t ws_size,
                              hipStream_t stream) {
    const float* x     = (const float*)d_in[0];
    const float* ea    = (const float*)d_in[1];
    const int*   eidx  = (const int*)d_in[2];
    const int*   batch = (const int*)d_in[3];
    const float* W1    = (const float*)d_in[4];
    const float* b1    = (const float*)d_in[5];
    const float* gamma = (const float*)d_in[6];
    const float* beta  = (const float*)d_in[7];
    const float* rmean = (const float*)d_in[8];
    const float* rvar  = (const float*)d_in[9];
    const float* W2    = (const float*)d_in[10];
    const float* b2    = (const float*)d_in[11];
    float* out = (float*)d_out;

    float* ws = (float*)d_ws;
    // ws layout (floats):
    float* w1nT     = ws;                    // 96*16 = 1536
    float* w1eT     = ws + 1536;             // 32*16 = 512
    float* cw       = ws + 2048;             // 33 (pad to 2048)
    float* y        = ws + 4096;             // N_NODES*16 = 1,600,000
    float* partials = ws + 4096 + (size_t)N_NODES * 16;  // EB_BLOCKS*128 = 160,000

    prep_kernel<<<1, 64, 0, stream>>>(W1, b1, gamma, beta, rmean, rvar, W2, b2, w1nT, w1eT, cw);
    node_proj_kernel<<<(N_NODES + 255) / 256, 256, 0, stream>>>(x, w1nT, y);
    edge_kernel<<<EB_BLOCKS, EB_THREADS, 0, stream>>>(ea, eidx, batch, y, w1eT, cw, partials);
    reduce_kernel<<<N_GRAPHS, 256, 0, stream>>>(partials, out);
}